// Round 10
// baseline (10883.834 us; speedup 1.0000x reference)
//
#include <hip/hip_runtime.h>
#include <hip/hip_bf16.h>

#define S_LEN 256
#define BATCH 64
#define EMB   300
#define EPAD  320
#define HID   512
#define G4H   2048
#define NCLS  25
#define TWOH  1024

using bf16 = __hip_bfloat16;
typedef short bf8v __attribute__((ext_vector_type(8)));   // 8 bf16 in 4 VGPRs
typedef float f32x4 __attribute__((ext_vector_type(4)));
typedef unsigned long long ull;

__device__ __forceinline__ float us2f(unsigned short u) {
    union { unsigned int i; float f; } v; v.i = ((unsigned int)u) << 16; return v.f;
}
__device__ __forceinline__ float sigm(float x) { return 1.f / (1.f + __expf(-x)); }

// ---------------- embedding gather: x[t][b][e] (bf16, padded to EPAD) ----------------
__global__ void embed_kernel(const int* __restrict__ ids,
                             const float* __restrict__ emb,
                             bf16* __restrict__ x)
{
    int r = blockIdx.x;            // r = t*BATCH + b
    int t = r >> 6, b = r & 63;
    int id = ids[b * S_LEN + t];
    const float* src = emb + (size_t)id * EMB;
    bf16* dst = x + (size_t)r * EPAD;
    for (int e = threadIdx.x; e < EPAD; e += blockDim.x) {
        float v = (e < EMB) ? src[e] : 0.f;
        dst[e] = __float2bfloat16(v);
    }
}

// ------- transpose recurrent weights to bf16: whTb[wl][u][g][k] = W[D+k][g*512+u] -------
__global__ void wtrans_kernel(const float* __restrict__ w_fw0, const float* __restrict__ w_bw0,
                              const float* __restrict__ w_fw1, const float* __restrict__ w_bw1,
                              bf16* __restrict__ whTb)
{
    __shared__ float tile[32][33];
    int wl = blockIdx.z;
    const float* W; int D;
    if (wl == 0)      { W = w_fw0; D = EMB; }
    else if (wl == 1) { W = w_bw0; D = EMB; }
    else if (wl == 2) { W = w_fw1; D = TWOH; }
    else              { W = w_bw1; D = TWOH; }
    int k0 = blockIdx.x * 32, n0 = blockIdx.y * 32;
    int tx = threadIdx.x, ty = threadIdx.y;
    tile[ty][tx] = W[(size_t)(D + k0 + ty) * G4H + n0 + tx];
    __syncthreads();
    int k = k0 + tx;
    int n = n0 + ty;                  // gate-major column index
    int u = n & 511, g = n >> 9;
    whTb[(((size_t)wl * 512 + u) * 4 + g) * 512 + k] = __float2bfloat16(tile[tx][ty]);
}

// ------- transpose INPUT weights to bf16: wxTb[wl][n][k] = W[k][n], k<D else 0 -------
__global__ void wxtrans_kernel(const float* __restrict__ w_fw0, const float* __restrict__ w_bw0,
                               const float* __restrict__ w_fw1, const float* __restrict__ w_bw1,
                               bf16* __restrict__ wxTb)
{
    __shared__ float tile[32][33];
    int wl = blockIdx.z;
    const float* W; int D;
    if (wl == 0)      { W = w_fw0; D = EMB; }
    else if (wl == 1) { W = w_bw0; D = EMB; }
    else if (wl == 2) { W = w_fw1; D = TWOH; }
    else              { W = w_bw1; D = TWOH; }
    int k0 = blockIdx.x * 32, n0 = blockIdx.y * 32;
    int tx = threadIdx.x, ty = threadIdx.y;
    float v = (k0 + ty < D) ? W[(size_t)(k0 + ty) * G4H + n0 + tx] : 0.f;
    tile[ty][tx] = v;
    __syncthreads();
    wxTb[((size_t)wl * G4H + n0 + ty) * 1024 + k0 + tx] = __float2bfloat16(tile[tx][ty]);
}

// -------- MFMA input-gate GEMM: Gt[z][t][n][b] = (gather(A) @ Wx + bias)^T --------
// 128x128x64 tile, 4 waves (2x2), reg-staged LDS with 16B-chunk XOR swizzle (T2).
__global__ __launch_bounds__(256)
void gates_mfma(const bf16* __restrict__ A, int strideA, int K,
                const bf16* __restrict__ wxTb,
                const float* __restrict__ b_fw, const float* __restrict__ b_bw,
                const int* __restrict__ lengths,
                bf16* __restrict__ Gt)
{
    const int z  = blockIdx.z;
    const int m0 = blockIdx.x * 128;
    const int n0 = blockIdx.y * 128;
    const int tid = threadIdx.x;
    const float* bias = z ? b_bw : b_fw;

    __shared__ __align__(16) unsigned short As[128 * 64];
    __shared__ __align__(16) unsigned short Bs[128 * 64];

    // staging: thread handles 4 chunks (16B) per tile; chunk q = j*256+tid
    const int ca = tid & 7;
    const bf16* srcA[4];
    const bf16* srcB[4];
    int lofs[4];
#pragma unroll
    for (int j = 0; j < 4; ++j) {
        int row = j * 32 + (tid >> 3);
        int r = m0 + row, t = r >> 6, b = r & 63;
        int st = t;
        if (z) { int len = lengths[b]; st = (t < len) ? (len - 1 - t) : t; }
        srcA[j] = A + (size_t)(st * 64 + b) * strideA + ca * 8;
        srcB[j] = wxTb + ((size_t)z * G4H + n0 + row) * 1024 + ca * 8;
        lofs[j] = row * 64 + ((ca ^ (row & 7)) << 3);
    }

    const int l = tid & 63, lo16 = l & 15, hi4 = l >> 4;
    const int wv = tid >> 6, wm = wv >> 1, wn = wv & 1;

    f32x4 acc[4][4];
#pragma unroll
    for (int mi = 0; mi < 4; ++mi)
#pragma unroll
        for (int ni = 0; ni < 4; ++ni)
#pragma unroll
            for (int rr = 0; rr < 4; ++rr) acc[mi][ni][rr] = 0.f;

    uint4 ra[4], rb[4];
#pragma unroll
    for (int j = 0; j < 4; ++j) {
        ra[j] = *reinterpret_cast<const uint4*>(srcA[j]);
        rb[j] = *reinterpret_cast<const uint4*>(srcB[j]);
    }

    const int nk = K >> 6;
    for (int kt = 0; kt < nk; ++kt) {
        __syncthreads();
#pragma unroll
        for (int j = 0; j < 4; ++j) {
            *reinterpret_cast<uint4*>(&As[lofs[j]]) = ra[j];
            *reinterpret_cast<uint4*>(&Bs[lofs[j]]) = rb[j];
        }
        __syncthreads();
        if (kt + 1 < nk) {
#pragma unroll
            for (int j = 0; j < 4; ++j) {
                srcA[j] += 64; srcB[j] += 64;
                ra[j] = *reinterpret_cast<const uint4*>(srcA[j]);
                rb[j] = *reinterpret_cast<const uint4*>(srcB[j]);
            }
        }
#pragma unroll
        for (int ks = 0; ks < 2; ++ks) {
            bf8v af[4], bfv[4];
#pragma unroll
            for (int mi = 0; mi < 4; ++mi) {
                int row = wm * 64 + mi * 16 + lo16;
                int c = ks * 4 + hi4;
                af[mi] = *reinterpret_cast<const bf8v*>(&As[row * 64 + ((c ^ (row & 7)) << 3)]);
            }
#pragma unroll
            for (int ni = 0; ni < 4; ++ni) {
                int row = wn * 64 + ni * 16 + lo16;
                int c = ks * 4 + hi4;
                bfv[ni] = *reinterpret_cast<const bf8v*>(&Bs[row * 64 + ((c ^ (row & 7)) << 3)]);
            }
#pragma unroll
            for (int mi = 0; mi < 4; ++mi)
#pragma unroll
                for (int ni = 0; ni < 4; ++ni)
                    acc[mi][ni] = __builtin_amdgcn_mfma_f32_16x16x32_bf16(
                        af[mi], bfv[ni], acc[mi][ni], 0, 0, 0);
        }
    }

    // epilogue: D row = m0+wm*64+mi*16+hi4*4+rr -> (t, b); col = n0+wn*64+ni*16+lo16
    float bv[4];
#pragma unroll
    for (int ni = 0; ni < 4; ++ni) bv[ni] = bias[n0 + wn * 64 + ni * 16 + lo16];
    const int tt = (m0 >> 6) + wm;
#pragma unroll
    for (int mi = 0; mi < 4; ++mi) {
        int b0 = mi * 16 + hi4 * 4;
#pragma unroll
        for (int ni = 0; ni < 4; ++ni) {
            int n = n0 + wn * 64 + ni * 16 + lo16;
            __align__(8) bf16 tmp[4];
#pragma unroll
            for (int rr = 0; rr < 4; ++rr)
                tmp[rr] = __float2bfloat16(acc[mi][ni][rr] + bv[ni]);
            bf16* gout = Gt + (((size_t)z * S_LEN + tt) * G4H + n) * BATCH + b0;
            *reinterpret_cast<ull*>(gout) = *reinterpret_cast<const ull*>(tmp);
        }
    }
}

// ---------------- persistent MFMA LSTM recurrence — FREE-RUNNING WAVES ----------------
// 32 blocks = 2 dirs x 16 u-tiles; 4 waves each; weights persistent in VGPR B-frags.
// NO LDS, NO __syncthreads in the loop: MFMA A-frags are contiguous 16B runs of
// h[b][k], agent-loaded directly (2x8B per frag, deep independent pipeline).
// Per-WAVE flags: each wave drains its own stores (vmcnt(0)) then stores 1 flag;
// consumers poll 64 flags with 64 lanes (1 load + __all). Waves drift freely;
// WAR on h ping-pong proven safe by flag ordering at wave granularity.
__global__ __launch_bounds__(256, 1)
void lstm_seq(const bf16* __restrict__ Gt, const bf16* __restrict__ whTb,
              const int* __restrict__ lengths, unsigned short* __restrict__ hbuf,
              unsigned int* __restrict__ flags, bf16* __restrict__ hcat)
{
    const int bx = blockIdx.x;       // 0..31
    const int d  = bx >> 4;
    const int nb = bx & 15;
    const int u0 = nb * 32;
    const int tid = threadIdx.x;
    const int w    = tid >> 6;
    const int l    = tid & 63;
    const int lo16 = l & 15;
    const int hi4  = l >> 4;
    const int du   = l & 7;
    const int g0   = (l >> 3) & 1;   // gate pair selector: 0 -> {i,f}, 1 -> {j,o}
    const int u    = u0 + w * 8 + du;
    const bool owner = (g0 == 0);
    const int wid  = nb * 4 + w;     // wave id within direction: 0..63

    // ---- persistent B fragments ----
    bf8v bfr[2][16];
#pragma unroll
    for (int nt = 0; nt < 2; ++nt) {
        const bf16* wrow = whTb + (((size_t)d * 512 + u) * 4 + (nt * 2 + g0)) * 512 + hi4 * 8;
#pragma unroll
        for (int kt = 0; kt < 16; ++kt)
            bfr[nt][kt] = *reinterpret_cast<const bf8v*>(wrow + kt * 32);
    }

    int   len_st[16];
    float c_st[16], h_st[16];
#pragma unroll
    for (int mt = 0; mt < 4; ++mt)
#pragma unroll
        for (int rr = 0; rr < 4; ++rr) {
            len_st[mt * 4 + rr] = lengths[mt * 16 + hi4 * 4 + rr];
            c_st[mt * 4 + rr] = 0.f; h_st[mt * 4 + rr] = 0.f;
        }

    for (int t = 0; t < S_LEN; ++t) {
        // ---- Gt prefetch (independent of h, issued before the poll) ----
        ull gv[2][4];
#pragma unroll
        for (int nt = 0; nt < 2; ++nt) {
            const bf16* gtp = Gt + (((size_t)(d * S_LEN + t)) * G4H
                                    + (size_t)(nt * 2 + g0) * 512 + u) * BATCH + hi4 * 4;
#pragma unroll
            for (int mt = 0; mt < 4; ++mt)
                gv[nt][mt] = *reinterpret_cast<const ull*>(gtp + mt * 16);
        }

        // ---- wait for all 64 producer waves of this direction (step t-1) ----
        if (t > 0) {
            const unsigned int* fb = flags + (size_t)(t - 1) * 128 + d * 64;
            while (!__all(__hip_atomic_load(fb + l, __ATOMIC_RELAXED,
                                            __HIP_MEMORY_SCOPE_AGENT) != 0u))
                __builtin_amdgcn_s_sleep(1);
        }

        // ---- acc init from prefetched Gt ----
        f32x4 acc[2][4];
#pragma unroll
        for (int nt = 0; nt < 2; ++nt)
#pragma unroll
            for (int mt = 0; mt < 4; ++mt) {
                const unsigned short* gs = reinterpret_cast<const unsigned short*>(&gv[nt][mt]);
                f32x4 av;
#pragma unroll
                for (int rr = 0; rr < 4; ++rr) av[rr] = us2f(gs[rr]);
                acc[nt][mt] = av;
            }

        // ---- direct A-frag agent loads + MFMA (compiler pipelines vmcnt) ----
        const unsigned short* hb = hbuf + (size_t)((t & 1) * 2 + d) * BATCH * HID;
#pragma unroll
        for (int kt = 0; kt < 16; ++kt) {
            bf8v a[4];
#pragma unroll
            for (int mt = 0; mt < 4; ++mt) {
                const unsigned short* ap = hb + (size_t)(mt * 16 + lo16) * HID
                                              + kt * 32 + hi4 * 8;
                union { ull q[2]; bf8v v; } cvt;
                cvt.q[0] = __hip_atomic_load(reinterpret_cast<const ull*>(ap),
                                             __ATOMIC_RELAXED, __HIP_MEMORY_SCOPE_AGENT);
                cvt.q[1] = __hip_atomic_load(reinterpret_cast<const ull*>(ap + 4),
                                             __ATOMIC_RELAXED, __HIP_MEMORY_SCOPE_AGENT);
                a[mt] = cvt.v;
            }
#pragma unroll
            for (int nt = 0; nt < 2; ++nt)
#pragma unroll
                for (int mt = 0; mt < 4; ++mt)
                    acc[nt][mt] = __builtin_amdgcn_mfma_f32_16x16x32_bf16(
                        a[mt], bfr[nt][kt], acc[nt][mt], 0, 0, 0);
        }

        // ---- gate merge + pointwise + h_{t+1} stores (agent, 2B) ----
        unsigned short* hdst = hbuf + (size_t)(((t + 1) & 1) * 2 + d) * BATCH * HID;
#pragma unroll
        for (int mt = 0; mt < 4; ++mt) {
            f32x4 vif0 = acc[0][mt], vif1 = acc[1][mt];
            float vj[4], vo[4];
#pragma unroll
            for (int rr = 0; rr < 4; ++rr) {
                vj[rr] = __shfl_xor(vif0[rr], 8, 64);
                vo[rr] = __shfl_xor(vif1[rr], 8, 64);
            }
            if (owner) {
#pragma unroll
                for (int rr = 0; rr < 4; ++rr) {
                    int idx = mt * 4 + rr;
                    bool msk = (t < len_st[idx]);
                    float i_ = sigm(vif0[rr]);
                    float j_ = tanhf(vj[rr]);
                    float f_ = sigm(vif1[rr] + 1.0f);   // FORGET_BIAS
                    float o_ = sigm(vo[rr]);
                    float cn = f_ * c_st[idx] + i_ * j_;
                    float hn = o_ * tanhf(cn);
                    if (msk) c_st[idx] = cn;
                    h_st[idx] = msk ? hn : h_st[idx];
                    int b = mt * 16 + hi4 * 4 + rr;
                    union { bf16 v; unsigned short s; } cv;
                    cv.v = __float2bfloat16(h_st[idx]);
                    __hip_atomic_store(hdst + (size_t)b * HID + u, cv.s,
                                       __ATOMIC_RELAXED, __HIP_MEMORY_SCOPE_AGENT);
                }
            }
        }

        // ---- per-wave drain + flag signal (no block barrier) ----
        asm volatile("s_waitcnt vmcnt(0)" ::: "memory");
        if (l == 0)
            __hip_atomic_store(&flags[(size_t)t * 128 + d * 64 + wid], 1u,
                               __ATOMIC_RELAXED, __HIP_MEMORY_SCOPE_AGENT);

        // ---- shadow: hcat stores ----
        if (owner) {
#pragma unroll
            for (int mt = 0; mt < 4; ++mt)
#pragma unroll
                for (int rr = 0; rr < 4; ++rr) {
                    int idx = mt * 4 + rr;
                    int b = mt * 16 + hi4 * 4 + rr;
                    bool msk = (t < len_st[idx]);
                    int p = (d == 1 && msk) ? (len_st[idx] - 1 - t) : t;
                    hcat[((size_t)p * BATCH + b) * TWOH + (size_t)d * HID + u] =
                        __float2bfloat16(msk ? h_st[idx] : 0.f);
                }
        }
    }
}

// ---------------- dense + softmax: out[b][s][c] ----------------
__global__ __launch_bounds__(256)
void dense_softmax(const bf16* __restrict__ h, const float* __restrict__ wd,
                   const float* __restrict__ bd, float* __restrict__ out)
{
    __shared__ __align__(16) bf16 wdT[NCLS][1032];
    for (int i = threadIdx.x; i < TWOH * NCLS; i += 256) {
        int k = i / NCLS, c = i % NCLS;    // wd[k][c]
        wdT[c][k] = __float2bfloat16(wd[i]);
    }
    __syncthreads();
    const int c  = threadIdx.x & 31;
    const int rl = threadIdx.x >> 5;
#pragma unroll 1
    for (int pass = 0; pass < 8; ++pass) {
        int r = blockIdx.x * 64 + pass * 8 + rl;   // r = s*BATCH + b
        const bf16* hrow = h + (size_t)r * TWOH;
        float acc = -1e30f;
        if (c < NCLS) {
            acc = 0.f;
            for (int k = 0; k < TWOH; k += 8) {
                uint4 hv = *reinterpret_cast<const uint4*>(hrow + k);
                uint4 wv = *reinterpret_cast<const uint4*>(&wdT[c][k]);
                const unsigned short* hs  = reinterpret_cast<const unsigned short*>(&hv);
                const unsigned short* wsp = reinterpret_cast<const unsigned short*>(&wv);
#pragma unroll
                for (int j = 0; j < 8; ++j) acc += us2f(hs[j]) * us2f(wsp[j]);
            }
            acc += bd[c];
        }
        float mx = acc;
#pragma unroll
        for (int o = 16; o; o >>= 1) mx = fmaxf(mx, __shfl_xor(mx, o, 32));
        float e = (c < NCLS) ? __expf(acc - mx) : 0.f;
        float sm = e;
#pragma unroll
        for (int o = 16; o; o >>= 1) sm += __shfl_xor(sm, o, 32);
        if (c < NCLS) {
            int s = r >> 6, b = r & 63;
            out[((size_t)b * S_LEN + s) * NCLS + c] = e / sm;
        }
    }
}

extern "C" void kernel_launch(void* const* d_in, const int* in_sizes, int n_in,
                              void* d_out, int out_size, void* d_ws, size_t ws_size,
                              hipStream_t stream)
{
    const int*   ids   = (const int*)  d_in[0];
    const int*   lens  = (const int*)  d_in[1];
    const float* emb   = (const float*)d_in[2];
    const float* w_fw0 = (const float*)d_in[3];
    const float* b_fw0 = (const float*)d_in[4];
    const float* w_bw0 = (const float*)d_in[5];
    const float* b_bw0 = (const float*)d_in[6];
    const float* w_fw1 = (const float*)d_in[7];
    const float* b_fw1 = (const float*)d_in[8];
    const float* w_bw1 = (const float*)d_in[9];
    const float* b_bw1 = (const float*)d_in[10];
    const float* wd    = (const float*)d_in[11];
    const float* bd    = (const float*)d_in[12];
    float* out = (float*)d_out;

    char* ws = (char*)d_ws;
    size_t off = 0;
    auto alloc = [&](size_t bytes) {
        void* p = ws + off;
        off += (bytes + 255) & ~(size_t)255;
        return p;
    };
    bf16*  x      = (bf16*) alloc((size_t)S_LEN * BATCH * EPAD * 2);
    bf16*  Gt     = (bf16*) alloc((size_t)2 * S_LEN * G4H * BATCH * 2);
    bf16*  hcat0  = (bf16*) alloc((size_t)S_LEN * BATCH * TWOH * 2);
    bf16*  hcat1  = (bf16*) alloc((size_t)S_LEN * BATCH * TWOH * 2);
    bf16*  whTb   = (bf16*) alloc((size_t)4 * 512 * 4 * 512 * 2);
    bf16*  wxTb   = (bf16*) alloc((size_t)4 * G4H * 1024 * 2);
    unsigned short* hbuf = (unsigned short*)alloc((size_t)2 * 2 * BATCH * HID * 2);
    unsigned int* flags  = (unsigned int*) alloc((size_t)S_LEN * 128 * 4);

    embed_kernel<<<S_LEN * BATCH, 128, 0, stream>>>(ids, emb, x);
    wtrans_kernel<<<dim3(16, 64, 4), dim3(32, 32), 0, stream>>>(w_fw0, w_bw0, w_fw1, w_bw1, whTb);
    wxtrans_kernel<<<dim3(32, 64, 4), dim3(32, 32), 0, stream>>>(w_fw0, w_bw0, w_fw1, w_bw1, wxTb);

    for (int layer = 0; layer < 2; ++layer) {
        hipMemsetAsync(hbuf, 0, (size_t)2 * 2 * BATCH * HID * 2, stream);
        hipMemsetAsync(flags, 0, (size_t)S_LEN * 128 * 4, stream);
        const bf16* Ain   = layer ? hcat0 : x;
        int strideA       = layer ? TWOH : EPAD;
        int K             = layer ? 1024 : EPAD;
        const float* bfp  = layer ? b_fw1 : b_fw0;
        const float* bbp  = layer ? b_bw1 : b_bw0;
        bf16* hcat        = layer ? hcat1 : hcat0;

        gates_mfma<<<dim3(128, 16, 2), 256, 0, stream>>>(
            Ain, strideA, K, wxTb + (size_t)layer * 2 * G4H * 1024,
            bfp, bbp, lens, Gt);

        const bf16*  Gp   = Gt;
        const bf16*  whp  = whTb + (size_t)layer * 2 * 512 * 4 * 512;
        const int*   lnp  = lens;
        unsigned short* hbp = hbuf;
        unsigned int* flp = flags;
        bf16*        hcp  = hcat;
        void* args[6] = { &Gp, &whp, &lnp, &hbp, &flp, &hcp };
        hipLaunchCooperativeKernel(lstm_seq, dim3(32), dim3(256), args, 0, stream);
    }
    dense_softmax<<<256, 256, 0, stream>>>(hcat1, wd, bd, out);

    (void)in_sizes; (void)n_in; (void)out_size; (void)ws_size;
}

// Round 11
// 4391.088 us; speedup vs baseline: 2.4786x; 2.4786x over previous
//
#include <hip/hip_runtime.h>
#include <hip/hip_bf16.h>

#define S_LEN 256
#define BATCH 64
#define EMB   300
#define EPAD  320
#define HID   512
#define G4H   2048
#define NCLS  25
#define TWOH  1024

using bf16 = __hip_bfloat16;
typedef short bf8v __attribute__((ext_vector_type(8)));   // 8 bf16 in 4 VGPRs
typedef float f32x4 __attribute__((ext_vector_type(4)));
typedef unsigned long long ull;

__device__ __forceinline__ float us2f(unsigned short u) {
    union { unsigned int i; float f; } v; v.i = ((unsigned int)u) << 16; return v.f;
}
__device__ __forceinline__ unsigned short f2us(float f) {
    union { bf16 v; unsigned short s; } cv; cv.v = __float2bfloat16(f); return cv.s;
}
__device__ __forceinline__ float sigm(float x) { return 1.f / (1.f + __expf(-x)); }

// ---------------- embedding gather: x[t][b][e] (bf16, padded to EPAD) ----------------
__global__ void embed_kernel(const int* __restrict__ ids,
                             const float* __restrict__ emb,
                             bf16* __restrict__ x)
{
    int r = blockIdx.x;            // r = t*BATCH + b
    int t = r >> 6, b = r & 63;
    int id = ids[b * S_LEN + t];
    const float* src = emb + (size_t)id * EMB;
    bf16* dst = x + (size_t)r * EPAD;
    for (int e = threadIdx.x; e < EPAD; e += blockDim.x) {
        float v = (e < EMB) ? src[e] : 0.f;
        dst[e] = __float2bfloat16(v);
    }
}

// ------- transpose recurrent weights to bf16: whTb[wl][u][g][k] = W[D+k][g*512+u] -------
__global__ void wtrans_kernel(const float* __restrict__ w_fw0, const float* __restrict__ w_bw0,
                              const float* __restrict__ w_fw1, const float* __restrict__ w_bw1,
                              bf16* __restrict__ whTb)
{
    __shared__ float tile[32][33];
    int wl = blockIdx.z;
    const float* W; int D;
    if (wl == 0)      { W = w_fw0; D = EMB; }
    else if (wl == 1) { W = w_bw0; D = EMB; }
    else if (wl == 2) { W = w_fw1; D = TWOH; }
    else              { W = w_bw1; D = TWOH; }
    int k0 = blockIdx.x * 32, n0 = blockIdx.y * 32;
    int tx = threadIdx.x, ty = threadIdx.y;
    tile[ty][tx] = W[(size_t)(D + k0 + ty) * G4H + n0 + tx];
    __syncthreads();
    int k = k0 + tx;
    int n = n0 + ty;                  // gate-major column index
    int u = n & 511, g = n >> 9;
    whTb[(((size_t)wl * 512 + u) * 4 + g) * 512 + k] = __float2bfloat16(tile[tx][ty]);
}

// ------- transpose INPUT weights to bf16: wxTb[wl][n][k] = W[k][n], k<D else 0 -------
__global__ void wxtrans_kernel(const float* __restrict__ w_fw0, const float* __restrict__ w_bw0,
                               const float* __restrict__ w_fw1, const float* __restrict__ w_bw1,
                               bf16* __restrict__ wxTb)
{
    __shared__ float tile[32][33];
    int wl = blockIdx.z;
    const float* W; int D;
    if (wl == 0)      { W = w_fw0; D = EMB; }
    else if (wl == 1) { W = w_bw0; D = EMB; }
    else if (wl == 2) { W = w_fw1; D = TWOH; }
    else              { W = w_bw1; D = TWOH; }
    int k0 = blockIdx.x * 32, n0 = blockIdx.y * 32;
    int tx = threadIdx.x, ty = threadIdx.y;
    float v = (k0 + ty < D) ? W[(size_t)(k0 + ty) * G4H + n0 + tx] : 0.f;
    tile[ty][tx] = v;
    __syncthreads();
    wxTb[((size_t)wl * G4H + n0 + ty) * 1024 + k0 + tx] = __float2bfloat16(tile[tx][ty]);
}

// -------- MFMA input-gate GEMM: G[z][t][b][n] = gather(A) @ Wx + bias --------
// 128x128x64 tile, 4 waves (2x2), reg-staged LDS with 16B-chunk XOR swizzle.
// Epilogue transposes via LDS bounce so G keeps the natural [t][b][n] layout.
__global__ __launch_bounds__(256)
void gates_mfma(const bf16* __restrict__ A, int strideA, int K,
                const bf16* __restrict__ wxTb,
                const float* __restrict__ b_fw, const float* __restrict__ b_bw,
                const int* __restrict__ lengths,
                bf16* __restrict__ G)
{
    const int z  = blockIdx.z;
    const int m0 = blockIdx.x * 128;
    const int n0 = blockIdx.y * 128;
    const int tid = threadIdx.x;
    const float* bias = z ? b_bw : b_fw;

    __shared__ __align__(16) unsigned short smem[128 * 132];  // staging (32KB) + bounce
    unsigned short* As = smem;
    unsigned short* Bs = smem + 8192;

    const int ca = tid & 7;
    const bf16* srcA[4];
    const bf16* srcB[4];
    int lofs[4];
#pragma unroll
    for (int j = 0; j < 4; ++j) {
        int row = j * 32 + (tid >> 3);
        int r = m0 + row, t = r >> 6, b = r & 63;
        int st = t;
        if (z) { int len = lengths[b]; st = (t < len) ? (len - 1 - t) : t; }
        srcA[j] = A + (size_t)(st * 64 + b) * strideA + ca * 8;
        srcB[j] = wxTb + ((size_t)z * G4H + n0 + row) * 1024 + ca * 8;
        lofs[j] = row * 64 + ((ca ^ (row & 7)) << 3);
    }

    const int l = tid & 63, lo16 = l & 15, hi4 = l >> 4;
    const int wv = tid >> 6, wm = wv >> 1, wn = wv & 1;

    f32x4 acc[4][4];
#pragma unroll
    for (int mi = 0; mi < 4; ++mi)
#pragma unroll
        for (int ni = 0; ni < 4; ++ni)
#pragma unroll
            for (int rr = 0; rr < 4; ++rr) acc[mi][ni][rr] = 0.f;

    uint4 ra[4], rb[4];
#pragma unroll
    for (int j = 0; j < 4; ++j) {
        ra[j] = *reinterpret_cast<const uint4*>(srcA[j]);
        rb[j] = *reinterpret_cast<const uint4*>(srcB[j]);
    }

    const int nk = K >> 6;
    for (int kt = 0; kt < nk; ++kt) {
        __syncthreads();
#pragma unroll
        for (int j = 0; j < 4; ++j) {
            *reinterpret_cast<uint4*>(&As[lofs[j]]) = ra[j];
            *reinterpret_cast<uint4*>(&Bs[lofs[j]]) = rb[j];
        }
        __syncthreads();
        if (kt + 1 < nk) {
#pragma unroll
            for (int j = 0; j < 4; ++j) {
                srcA[j] += 64; srcB[j] += 64;
                ra[j] = *reinterpret_cast<const uint4*>(srcA[j]);
                rb[j] = *reinterpret_cast<const uint4*>(srcB[j]);
            }
        }
#pragma unroll
        for (int ks = 0; ks < 2; ++ks) {
            bf8v af[4], bfv[4];
#pragma unroll
            for (int mi = 0; mi < 4; ++mi) {
                int row = wm * 64 + mi * 16 + lo16;
                int c = ks * 4 + hi4;
                af[mi] = *reinterpret_cast<const bf8v*>(&As[row * 64 + ((c ^ (row & 7)) << 3)]);
            }
#pragma unroll
            for (int ni = 0; ni < 4; ++ni) {
                int row = wn * 64 + ni * 16 + lo16;
                int c = ks * 4 + hi4;
                bfv[ni] = *reinterpret_cast<const bf8v*>(&Bs[row * 64 + ((c ^ (row & 7)) << 3)]);
            }
#pragma unroll
            for (int mi = 0; mi < 4; ++mi)
#pragma unroll
                for (int ni = 0; ni < 4; ++ni)
                    acc[mi][ni] = __builtin_amdgcn_mfma_f32_16x16x32_bf16(
                        af[mi], bfv[ni], acc[mi][ni], 0, 0, 0);
        }
    }

    // ---- epilogue: LDS bounce to write G[t][b][n] row-major with wide stores ----
    __syncthreads();
    float bv[4];
#pragma unroll
    for (int ni = 0; ni < 4; ++ni) bv[ni] = bias[n0 + wn * 64 + ni * 16 + lo16];
#pragma unroll
    for (int mi = 0; mi < 4; ++mi)
#pragma unroll
        for (int ni = 0; ni < 4; ++ni)
#pragma unroll
            for (int rr = 0; rr < 4; ++rr) {
                int m = wm * 64 + mi * 16 + hi4 * 4 + rr;
                int n = wn * 64 + ni * 16 + lo16;
                smem[m * 132 + n] = f2us(acc[mi][ni][rr] + bv[ni]);
            }
    __syncthreads();
    {
        int m = tid >> 1;
        int t = (m0 + m) >> 6, b = (m0 + m) & 63;
        const unsigned short* src = smem + m * 132 + (tid & 1) * 64;
        bf16* gout = G + (((size_t)z * S_LEN + t) * BATCH + b) * G4H + n0 + (tid & 1) * 64;
#pragma unroll
        for (int j = 0; j < 16; ++j)
            *reinterpret_cast<ull*>(gout + j * 4) = *reinterpret_cast<const ull*>(src + j * 4);
    }
}

// ---------------- persistent MFMA LSTM recurrence (one layer, both dirs) ----------------
// 32 blocks = 2 dirs x 8 u-groups x 2 b-halves; 4 waves = 16u x 32b each.
// Operands swapped vs R9: A = weights (L2-resident, re-read per kt), B = h (LDS-staged,
// 32KB/block). D = gates[u][b]: all 4 gates for (b,u) on ONE lane -> no shuffles, all-lane
// pointwise, h stores are contiguous 8B. R9 flag barrier (store-once, narrow poll) kept.
__global__ __launch_bounds__(256, 1)
void lstm_seq(const bf16* __restrict__ G, const bf16* __restrict__ whTb,
              const int* __restrict__ lengths, unsigned short* __restrict__ hbuf,
              unsigned int* __restrict__ flags, bf16* __restrict__ hcat)
{
    __shared__ __align__(16) unsigned short hl[32 * 512];   // 32KB h tile, swizzled chunks

    const int bx    = blockIdx.x;     // 0..31
    const int d     = bx >> 4;
    const int blk   = bx & 15;
    const int ub    = blk >> 1;       // u-group 0..7
    const int bhalf = blk & 1;
    const int b_base = bhalf * 32;
    const int tid = threadIdx.x;
    const int w   = tid >> 6;
    const int l   = tid & 63;
    const int lo16 = l & 15, hi4 = l >> 4;
    const int u0w  = ub * 64 + w * 16;          // wave's 16-unit base
    const int urow = u0w + lo16;                // A-frag row (unit)
    const int b0   = b_base + lo16;             // btile0 batch
    const int b1   = b_base + 16 + lo16;        // btile1 batch

    // weight row pointers (A-frag: lane row = lo16, k = hi4*8 + j); frag (g,kt) at +kt*32
    const bf16* wgp[4];
#pragma unroll
    for (int g = 0; g < 4; ++g)
        wgp[g] = whTb + (((size_t)d * 512 + urow) * 4 + g) * 512 + hi4 * 8;

    const int len0 = lengths[b0], len1 = lengths[b1];
    f32x4 c_st[2], h_st[2];
#pragma unroll
    for (int bt = 0; bt < 2; ++bt)
#pragma unroll
        for (int rr = 0; rr < 4; ++rr) { c_st[bt][rr] = 0.f; h_st[bt][rr] = 0.f; }

    for (int t = 0; t < S_LEN; ++t) {
        // ---- stage h: 32 b x 512 k = 4096 ull words, 16 coalesced 8B loads/thread ----
        const ull* hsrc = reinterpret_cast<const ull*>(
            hbuf + (size_t)((t & 1) * 2 + d) * BATCH * HID) + (size_t)b_base * 128;
        ull pv[16];
#pragma unroll
        for (int i = 0; i < 16; ++i)
            pv[i] = __hip_atomic_load(hsrc + i * 256 + tid,
                                      __ATOMIC_RELAXED, __HIP_MEMORY_SCOPE_AGENT);

        // ---- G loads (issued after pv so LDS write only waits on pv) ----
        const bf16* gbase = G + ((size_t)(d * S_LEN + t) * BATCH) * G4H;
        ull gv[4][2];
#pragma unroll
        for (int g = 0; g < 4; ++g)
#pragma unroll
            for (int bt = 0; bt < 2; ++bt)
                gv[g][bt] = *reinterpret_cast<const ull*>(
                    gbase + (size_t)(b_base + bt * 16 + lo16) * G4H + g * 512 + u0w + hi4 * 4);

        __syncthreads();                 // prior step's MFMA reads of hl done
#pragma unroll
        for (int i = 0; i < 16; ++i) {
            int wd_ = i * 256 + tid;     // 8B word: b_local = wd>>7, word-in-row = wd&127
            int bl = wd_ >> 7, r = wd_ & 127;
            int c = r >> 1, half = r & 1;
            *reinterpret_cast<ull*>(&hl[bl * 512 + ((c ^ (bl & 7)) << 3) + (half << 2)]) = pv[i];
        }
        __syncthreads();

        // ---- acc init from G ----
        f32x4 acc[4][2];
#pragma unroll
        for (int g = 0; g < 4; ++g)
#pragma unroll
            for (int bt = 0; bt < 2; ++bt) {
                const unsigned short* gs = reinterpret_cast<const unsigned short*>(&gv[g][bt]);
                f32x4 av;
#pragma unroll
                for (int rr = 0; rr < 4; ++rr) av[rr] = us2f(gs[rr]);
                acc[g][bt] = av;
            }

        // ---- MFMA: 16 kt x (4 weight A-frags from L2 + 2 h B-frags from LDS + 8 mfma) ----
#pragma unroll
        for (int kt = 0; kt < 16; ++kt) {
            int c = kt * 4 + hi4;
            bf8v bv0 = *reinterpret_cast<const bf8v*>(
                &hl[lo16 * 512 + ((c ^ (lo16 & 7)) << 3)]);
            bf8v bv1 = *reinterpret_cast<const bf8v*>(
                &hl[(16 + lo16) * 512 + ((c ^ (lo16 & 7)) << 3)]);
            bf8v wf[4];
#pragma unroll
            for (int g = 0; g < 4; ++g)
                wf[g] = *reinterpret_cast<const bf8v*>(wgp[g] + kt * 32);
#pragma unroll
            for (int g = 0; g < 4; ++g) {
                acc[g][0] = __builtin_amdgcn_mfma_f32_16x16x32_bf16(wf[g], bv0, acc[g][0], 0, 0, 0);
                acc[g][1] = __builtin_amdgcn_mfma_f32_16x16x32_bf16(wf[g], bv1, acc[g][1], 0, 0, 0);
            }
        }

        // ---- pointwise: all lanes, 4 gates on-lane, 8B contiguous h stores ----
        unsigned short* hdst = hbuf + (size_t)(((t + 1) & 1) * 2 + d) * BATCH * HID;
#pragma unroll
        for (int bt = 0; bt < 2; ++bt) {
            int lenb = bt ? len1 : len0;
            int b    = bt ? b1 : b0;
            bool msk = (t < lenb);
#pragma unroll
            for (int rr = 0; rr < 4; ++rr) {
                float i_ = sigm(acc[0][bt][rr]);
                float j_ = tanhf(acc[1][bt][rr]);
                float f_ = sigm(acc[2][bt][rr] + 1.0f);   // FORGET_BIAS
                float o_ = sigm(acc[3][bt][rr]);
                float cn = f_ * c_st[bt][rr] + i_ * j_;
                float hn = o_ * tanhf(cn);
                if (msk) c_st[bt][rr] = cn;
                h_st[bt][rr] = msk ? hn : h_st[bt][rr];
            }
            union { unsigned short s[4]; ull q; } hw;
#pragma unroll
            for (int rr = 0; rr < 4; ++rr) hw.s[rr] = f2us(h_st[bt][rr]);
            __hip_atomic_store(reinterpret_cast<ull*>(
                hdst + (size_t)b * HID + u0w + hi4 * 4), hw.q,
                __ATOMIC_RELAXED, __HIP_MEMORY_SCOPE_AGENT);
        }

        // ---- drain + signal early ----
        asm volatile("s_waitcnt vmcnt(0)" ::: "memory");
        __syncthreads();
        if (tid == 0)
            __hip_atomic_store(&flags[(size_t)t * 32 + d * 16 + blk], 1u,
                               __ATOMIC_RELAXED, __HIP_MEMORY_SCOPE_AGENT);

        // ---- shadow: hcat stores (8B contiguous) ----
#pragma unroll
        for (int bt = 0; bt < 2; ++bt) {
            int lenb = bt ? len1 : len0;
            int b    = bt ? b1 : b0;
            bool msk = (t < lenb);
            int p = (d == 1 && msk) ? (lenb - 1 - t) : t;
            union { unsigned short s[4]; ull q; } hw;
#pragma unroll
            for (int rr = 0; rr < 4; ++rr) hw.s[rr] = msk ? f2us(h_st[bt][rr]) : 0;
            *reinterpret_cast<ull*>(
                hcat + ((size_t)p * BATCH + b) * TWOH + (size_t)d * HID + u0w + hi4 * 4) = hw.q;
        }

        // ---- wait: poll this direction's 16 flags (read-only, narrow) ----
        if (tid < 16) {
            const unsigned int* fb = flags + (size_t)t * 32 + d * 16;
            while (__hip_atomic_load(fb + tid, __ATOMIC_RELAXED,
                                     __HIP_MEMORY_SCOPE_AGENT) == 0u)
                __builtin_amdgcn_s_sleep(2);
        }
        __syncthreads();
    }
}

// ---------------- dense + softmax: out[b][s][c] ----------------
__global__ __launch_bounds__(256)
void dense_softmax(const bf16* __restrict__ h, const float* __restrict__ wd,
                   const float* __restrict__ bd, float* __restrict__ out)
{
    __shared__ __align__(16) bf16 wdT[NCLS][1032];
    for (int i = threadIdx.x; i < TWOH * NCLS; i += 256) {
        int k = i / NCLS, c = i % NCLS;    // wd[k][c]
        wdT[c][k] = __float2bfloat16(wd[i]);
    }
    __syncthreads();
    const int c  = threadIdx.x & 31;
    const int rl = threadIdx.x >> 5;
#pragma unroll 1
    for (int pass = 0; pass < 8; ++pass) {
        int r = blockIdx.x * 64 + pass * 8 + rl;   // r = s*BATCH + b
        const bf16* hrow = h + (size_t)r * TWOH;
        float acc = -1e30f;
        if (c < NCLS) {
            acc = 0.f;
            for (int k = 0; k < TWOH; k += 8) {
                uint4 hv = *reinterpret_cast<const uint4*>(hrow + k);
                uint4 wv = *reinterpret_cast<const uint4*>(&wdT[c][k]);
                const unsigned short* hs  = reinterpret_cast<const unsigned short*>(&hv);
                const unsigned short* wsp = reinterpret_cast<const unsigned short*>(&wv);
#pragma unroll
                for (int j = 0; j < 8; ++j) acc += us2f(hs[j]) * us2f(wsp[j]);
            }
            acc += bd[c];
        }
        float mx = acc;
#pragma unroll
        for (int o = 16; o; o >>= 1) mx = fmaxf(mx, __shfl_xor(mx, o, 32));
        float e = (c < NCLS) ? __expf(acc - mx) : 0.f;
        float sm = e;
#pragma unroll
        for (int o = 16; o; o >>= 1) sm += __shfl_xor(sm, o, 32);
        if (c < NCLS) {
            int s = r >> 6, b = r & 63;
            out[((size_t)b * S_LEN + s) * NCLS + c] = e / sm;
        }
    }
}

extern "C" void kernel_launch(void* const* d_in, const int* in_sizes, int n_in,
                              void* d_out, int out_size, void* d_ws, size_t ws_size,
                              hipStream_t stream)
{
    const int*   ids   = (const int*)  d_in[0];
    const int*   lens  = (const int*)  d_in[1];
    const float* emb   = (const float*)d_in[2];
    const float* w_fw0 = (const float*)d_in[3];
    const float* b_fw0 = (const float*)d_in[4];
    const float* w_bw0 = (const float*)d_in[5];
    const float* b_bw0 = (const float*)d_in[6];
    const float* w_fw1 = (const float*)d_in[7];
    const float* b_fw1 = (const float*)d_in[8];
    const float* w_bw1 = (const float*)d_in[9];
    const float* b_bw1 = (const float*)d_in[10];
    const float* wd    = (const float*)d_in[11];
    const float* bd    = (const float*)d_in[12];
    float* out = (float*)d_out;

    char* ws = (char*)d_ws;
    size_t off = 0;
    auto alloc = [&](size_t bytes) {
        void* p = ws + off;
        off += (bytes + 255) & ~(size_t)255;
        return p;
    };
    bf16*  x      = (bf16*) alloc((size_t)S_LEN * BATCH * EPAD * 2);
    bf16*  G      = (bf16*) alloc((size_t)2 * S_LEN * BATCH * G4H * 2);
    bf16*  hcat0  = (bf16*) alloc((size_t)S_LEN * BATCH * TWOH * 2);
    bf16*  hcat1  = (bf16*) alloc((size_t)S_LEN * BATCH * TWOH * 2);
    bf16*  whTb   = (bf16*) alloc((size_t)4 * 512 * 4 * 512 * 2);
    bf16*  wxTb   = (bf16*) alloc((size_t)4 * G4H * 1024 * 2);
    unsigned short* hbuf = (unsigned short*)alloc((size_t)2 * 2 * BATCH * HID * 2);
    unsigned int* flags  = (unsigned int*) alloc((size_t)S_LEN * 32 * 4);

    embed_kernel<<<S_LEN * BATCH, 128, 0, stream>>>(ids, emb, x);
    wtrans_kernel<<<dim3(16, 64, 4), dim3(32, 32), 0, stream>>>(w_fw0, w_bw0, w_fw1, w_bw1, whTb);
    wxtrans_kernel<<<dim3(32, 64, 4), dim3(32, 32), 0, stream>>>(w_fw0, w_bw0, w_fw1, w_bw1, wxTb);

    for (int layer = 0; layer < 2; ++layer) {
        hipMemsetAsync(hbuf, 0, (size_t)2 * 2 * BATCH * HID * 2, stream);
        hipMemsetAsync(flags, 0, (size_t)S_LEN * 32 * 4, stream);
        const bf16* Ain   = layer ? hcat0 : x;
        int strideA       = layer ? TWOH : EPAD;
        int K             = layer ? 1024 : EPAD;
        const float* bfp  = layer ? b_fw1 : b_fw0;
        const float* bbp  = layer ? b_bw1 : b_bw0;
        bf16* hcat        = layer ? hcat1 : hcat0;

        gates_mfma<<<dim3(128, 16, 2), 256, 0, stream>>>(
            Ain, strideA, K, wxTb + (size_t)layer * 2 * G4H * 1024,
            bfp, bbp, lens, G);

        const bf16*  Gp   = G;
        const bf16*  whp  = whTb + (size_t)layer * 2 * 512 * 4 * 512;
        const int*   lnp  = lens;
        unsigned short* hbp = hbuf;
        unsigned int* flp = flags;
        bf16*        hcp  = hcat;
        void* args[6] = { &Gp, &whp, &lnp, &hbp, &flp, &hcp };
        hipLaunchCooperativeKernel(lstm_seq, dim3(32), dim3(256), args, 0, stream);
    }
    dense_softmax<<<256, 256, 0, stream>>>(hcat1, wd, bd, out);

    (void)in_sizes; (void)n_in; (void)out_size; (void)ws_size;
}

// Round 12
// 3836.599 us; speedup vs baseline: 2.8368x; 1.1445x over previous
//
#include <hip/hip_runtime.h>
#include <hip/hip_bf16.h>

#define S_LEN 256
#define BATCH 64
#define EMB   300
#define EPAD  320
#define HID   512
#define G4H   2048
#define NCLS  25
#define TWOH  1024

using bf16 = __hip_bfloat16;
typedef short bf8v __attribute__((ext_vector_type(8)));   // 8 bf16 in 4 VGPRs
typedef float f32x4 __attribute__((ext_vector_type(4)));
typedef unsigned long long ull;

__device__ __forceinline__ float us2f(unsigned short u) {
    union { unsigned int i; float f; } v; v.i = ((unsigned int)u) << 16; return v.f;
}
__device__ __forceinline__ unsigned short f2us(float f) {
    union { bf16 v; unsigned short s; } cv; cv.v = __float2bfloat16(f); return cv.s;
}
__device__ __forceinline__ float sigm(float x) { return 1.f / (1.f + __expf(-x)); }

// ---------------- embedding gather: x[t][b][e] (bf16, padded to EPAD) ----------------
__global__ void embed_kernel(const int* __restrict__ ids,
                             const float* __restrict__ emb,
                             bf16* __restrict__ x)
{
    int r = blockIdx.x;            // r = t*BATCH + b
    int t = r >> 6, b = r & 63;
    int id = ids[b * S_LEN + t];
    const float* src = emb + (size_t)id * EMB;
    bf16* dst = x + (size_t)r * EPAD;
    for (int e = threadIdx.x; e < EPAD; e += blockDim.x) {
        float v = (e < EMB) ? src[e] : 0.f;
        dst[e] = __float2bfloat16(v);
    }
}

// ------- transpose recurrent weights to bf16: whTb[wl][u][g][k] = W[D+k][g*512+u] -------
__global__ void wtrans_kernel(const float* __restrict__ w_fw0, const float* __restrict__ w_bw0,
                              const float* __restrict__ w_fw1, const float* __restrict__ w_bw1,
                              bf16* __restrict__ whTb)
{
    __shared__ float tile[32][33];
    int wl = blockIdx.z;
    const float* W; int D;
    if (wl == 0)      { W = w_fw0; D = EMB; }
    else if (wl == 1) { W = w_bw0; D = EMB; }
    else if (wl == 2) { W = w_fw1; D = TWOH; }
    else              { W = w_bw1; D = TWOH; }
    int k0 = blockIdx.x * 32, n0 = blockIdx.y * 32;
    int tx = threadIdx.x, ty = threadIdx.y;
    tile[ty][tx] = W[(size_t)(D + k0 + ty) * G4H + n0 + tx];
    __syncthreads();
    int k = k0 + tx;
    int n = n0 + ty;                  // raw TF col: n = g*512 + u
    int u = n & 511, g = n >> 9;
    whTb[(((size_t)wl * 512 + u) * 4 + g) * 512 + k] = __float2bfloat16(tile[tx][ty]);
}

// --- transpose INPUT weights to bf16, gate-interleaved cols: wxTb[wl][u*4+g][k] ---
__global__ void wxtrans_kernel(const float* __restrict__ w_fw0, const float* __restrict__ w_bw0,
                               const float* __restrict__ w_fw1, const float* __restrict__ w_bw1,
                               bf16* __restrict__ wxTb)
{
    __shared__ float tile[32][33];
    int wl = blockIdx.z;
    const float* W; int D;
    if (wl == 0)      { W = w_fw0; D = EMB; }
    else if (wl == 1) { W = w_bw0; D = EMB; }
    else if (wl == 2) { W = w_fw1; D = TWOH; }
    else              { W = w_bw1; D = TWOH; }
    int k0 = blockIdx.x * 32, n0 = blockIdx.y * 32;
    int tx = threadIdx.x, ty = threadIdx.y;
    float v = (k0 + ty < D) ? W[(size_t)(k0 + ty) * G4H + n0 + tx] : 0.f;
    tile[ty][tx] = v;
    __syncthreads();
    int n = n0 + ty;                  // raw col -> interleaved row u*4+g
    int u = n & 511, g = n >> 9;
    wxTb[((size_t)wl * G4H + (u * 4 + g)) * 1024 + k0 + tx] = __float2bfloat16(tile[tx][ty]);
}

// -------- MFMA input-gate GEMM: G4[z][t][b][u*4+g] = gather(A) @ Wx + bias --------
// 128x128x64 tile, 4 waves (2x2), reg-staged LDS with 16B-chunk XOR swizzle.
// wxTb cols are gate-interleaved (u*4+g) so the epilogue stays contiguous.
__global__ __launch_bounds__(256)
void gates_mfma(const bf16* __restrict__ A, int strideA, int K,
                const bf16* __restrict__ wxTb,
                const float* __restrict__ b_fw, const float* __restrict__ b_bw,
                const int* __restrict__ lengths,
                bf16* __restrict__ G4)
{
    const int z  = blockIdx.z;
    const int m0 = blockIdx.x * 128;
    const int n0 = blockIdx.y * 128;
    const int tid = threadIdx.x;
    const float* bias = z ? b_bw : b_fw;

    __shared__ __align__(16) unsigned short smem[128 * 132];  // staging (32KB) + bounce
    unsigned short* As = smem;
    unsigned short* Bs = smem + 8192;

    const int ca = tid & 7;
    const bf16* srcA[4];
    const bf16* srcB[4];
    int lofs[4];
#pragma unroll
    for (int j = 0; j < 4; ++j) {
        int row = j * 32 + (tid >> 3);
        int r = m0 + row, t = r >> 6, b = r & 63;
        int st = t;
        if (z) { int len = lengths[b]; st = (t < len) ? (len - 1 - t) : t; }
        srcA[j] = A + (size_t)(st * 64 + b) * strideA + ca * 8;
        srcB[j] = wxTb + ((size_t)z * G4H + n0 + row) * 1024 + ca * 8;
        lofs[j] = row * 64 + ((ca ^ (row & 7)) << 3);
    }

    const int l = tid & 63, lo16 = l & 15, hi4 = l >> 4;
    const int wv = tid >> 6, wm = wv >> 1, wn = wv & 1;

    f32x4 acc[4][4];
#pragma unroll
    for (int mi = 0; mi < 4; ++mi)
#pragma unroll
        for (int ni = 0; ni < 4; ++ni)
#pragma unroll
            for (int rr = 0; rr < 4; ++rr) acc[mi][ni][rr] = 0.f;

    uint4 ra[4], rb[4];
#pragma unroll
    for (int j = 0; j < 4; ++j) {
        ra[j] = *reinterpret_cast<const uint4*>(srcA[j]);
        rb[j] = *reinterpret_cast<const uint4*>(srcB[j]);
    }

    const int nk = K >> 6;
    for (int kt = 0; kt < nk; ++kt) {
        __syncthreads();
#pragma unroll
        for (int j = 0; j < 4; ++j) {
            *reinterpret_cast<uint4*>(&As[lofs[j]]) = ra[j];
            *reinterpret_cast<uint4*>(&Bs[lofs[j]]) = rb[j];
        }
        __syncthreads();
        if (kt + 1 < nk) {
#pragma unroll
            for (int j = 0; j < 4; ++j) {
                srcA[j] += 64; srcB[j] += 64;
                ra[j] = *reinterpret_cast<const uint4*>(srcA[j]);
                rb[j] = *reinterpret_cast<const uint4*>(srcB[j]);
            }
        }
#pragma unroll
        for (int ks = 0; ks < 2; ++ks) {
            bf8v af[4], bfv[4];
#pragma unroll
            for (int mi = 0; mi < 4; ++mi) {
                int row = wm * 64 + mi * 16 + lo16;
                int c = ks * 4 + hi4;
                af[mi] = *reinterpret_cast<const bf8v*>(&As[row * 64 + ((c ^ (row & 7)) << 3)]);
            }
#pragma unroll
            for (int ni = 0; ni < 4; ++ni) {
                int row = wn * 64 + ni * 16 + lo16;
                int c = ks * 4 + hi4;
                bfv[ni] = *reinterpret_cast<const bf8v*>(&Bs[row * 64 + ((c ^ (row & 7)) << 3)]);
            }
#pragma unroll
            for (int mi = 0; mi < 4; ++mi)
#pragma unroll
                for (int ni = 0; ni < 4; ++ni)
                    acc[mi][ni] = __builtin_amdgcn_mfma_f32_16x16x32_bf16(
                        af[mi], bfv[ni], acc[mi][ni], 0, 0, 0);
        }
    }

    // ---- epilogue: LDS bounce, then contiguous [b][u*4+g] row writes ----
    __syncthreads();
    float bv[4];
#pragma unroll
    for (int ni = 0; ni < 4; ++ni) {
        int np = n0 + wn * 64 + ni * 16 + lo16;      // interleaved col
        int raw = (np & 3) * 512 + (np >> 2);        // raw TF bias index g*512+u
        bv[ni] = bias[raw];
    }
#pragma unroll
    for (int mi = 0; mi < 4; ++mi)
#pragma unroll
        for (int ni = 0; ni < 4; ++ni)
#pragma unroll
            for (int rr = 0; rr < 4; ++rr) {
                int m = wm * 64 + mi * 16 + hi4 * 4 + rr;
                int n = wn * 64 + ni * 16 + lo16;
                smem[m * 132 + n] = f2us(acc[mi][ni][rr] + bv[ni]);
            }
    __syncthreads();
    {
        int m = tid >> 1;
        int t = (m0 + m) >> 6, b = (m0 + m) & 63;
        const unsigned short* src = smem + m * 132 + (tid & 1) * 64;
        bf16* gout = G4 + (((size_t)z * S_LEN + t) * 64 + b) * G4H + n0 + (tid & 1) * 64;
#pragma unroll
        for (int j = 0; j < 16; ++j)
            *reinterpret_cast<ull*>(gout + j * 4) = *reinterpret_cast<const ull*>(src + j * 4);
    }
}

// ---------------- persistent MFMA LSTM recurrence (one layer, both dirs) ----------------
// 32 blocks = 2 dirs x 2 b-halves x 8 col-groups; 512 threads (8 waves).
// Block = 64 units x 32 batches. Wave = 8u x 32b; cols packed [u][g] so a wave's
// weights = 2 M-tiles x 16 kt = 128 persistent VGPRs (ZERO per-step weight traffic),
// and D regs = the 4 gates of one (u,b) -> no shuffles. h exchange: LDS-staged
// coalesced agent loads + LDS-bounce coalesced 8B stores. Sync: per-(d,bh) group of
// 8 blocks, store-once flags polled at loop top (narrow, read-only).
__global__ __launch_bounds__(512, 1)
void lstm_seq(const bf16* __restrict__ G4, const bf16* __restrict__ whTb,
              const int* __restrict__ lengths, unsigned short* __restrict__ hbuf,
              unsigned int* __restrict__ flags, bf16* __restrict__ hcat)
{
    __shared__ __align__(16) unsigned short hl[32 * 512];    // 32KB h tile (swizzled)
    __shared__ __align__(16) unsigned short hout[32 * 64];   // 4KB store bounce

    const int bx = blockIdx.x;          // 0..31
    const int d  = bx >> 4;
    const int bh = (bx >> 3) & 1;
    const int cg = bx & 7;
    const int tid = threadIdx.x;        // 0..511
    const int w = tid >> 6, l = tid & 63;
    const int lo16 = l & 15, hi4 = l >> 4;
    const int u0 = cg * 64 + w * 8;

    // ---- persistent weight A-frags: row lo16 -> (u_loc=lo16>>2, g=lo16&3) ----
    bf8v afr[2][16];
#pragma unroll
    for (int mt = 0; mt < 2; ++mt) {
        const bf16* wr = whTb + (((size_t)d * 512 + u0 + mt * 4 + (lo16 >> 2)) * 4
                                 + (lo16 & 3)) * 512 + hi4 * 8;
#pragma unroll
        for (int kt = 0; kt < 16; ++kt)
            afr[mt][kt] = *reinterpret_cast<const bf8v*>(wr + kt * 32);
    }

    int len_[2];
    float c_st[2][2], h_st[2][2];
#pragma unroll
    for (int nt = 0; nt < 2; ++nt) {
        len_[nt] = lengths[bh * 32 + nt * 16 + lo16];
#pragma unroll
        for (int mt = 0; mt < 2; ++mt) { c_st[mt][nt] = 0.f; h_st[mt][nt] = 0.f; }
    }

    for (int t = 0; t < S_LEN; ++t) {
        // ---- G loads early (stable data, hides under poll) ----
        ull gv[2][2];
#pragma unroll
        for (int mt = 0; mt < 2; ++mt)
#pragma unroll
            for (int nt = 0; nt < 2; ++nt) {
                int b = bh * 32 + nt * 16 + lo16;
                int u = u0 + mt * 4 + hi4;
                gv[mt][nt] = *reinterpret_cast<const ull*>(
                    G4 + (((size_t)(d * S_LEN + t)) * 64 + b) * G4H + u * 4);
            }

        // ---- wait for the 8 producer blocks of (d,bh) to finish step t-1 ----
        if (t > 0 && tid < 8) {
            const unsigned int* fb = flags + (size_t)(t - 1) * 32 + (d * 2 + bh) * 8;
            while (__hip_atomic_load(fb + tid, __ATOMIC_RELAXED,
                                     __HIP_MEMORY_SCOPE_AGENT) == 0u)
                __builtin_amdgcn_s_sleep(2);
        }
        __syncthreads();        // poll done + prior step's MFMA reads of hl done

        // ---- stage h: 32b x 512u = 4096 ull, 8 coalesced loads/thread ----
        const ull* hsrc = reinterpret_cast<const ull*>(
            hbuf + ((size_t)((t & 1) * 2 + d) * 64 + bh * 32) * 512);
        ull pv[8];
#pragma unroll
        for (int i = 0; i < 8; ++i)
            pv[i] = __hip_atomic_load(hsrc + i * 512 + tid,
                                      __ATOMIC_RELAXED, __HIP_MEMORY_SCOPE_AGENT);
#pragma unroll
        for (int i = 0; i < 8; ++i) {
            int wd_ = i * 512 + tid;     // 8B word: bl = wd>>7, r = wd&127
            int bl = wd_ >> 7, r = wd_ & 127;
            int c = r >> 1, half = r & 1;
            *reinterpret_cast<ull*>(&hl[bl * 512 + ((c ^ (bl & 7)) << 3) + (half << 2)]) = pv[i];
        }
        __syncthreads();

        // ---- acc init from G4 (reg g = gate) ----
        f32x4 acc[2][2];
#pragma unroll
        for (int mt = 0; mt < 2; ++mt)
#pragma unroll
            for (int nt = 0; nt < 2; ++nt) {
                const unsigned short* gs = reinterpret_cast<const unsigned short*>(&gv[mt][nt]);
                f32x4 av;
#pragma unroll
                for (int g = 0; g < 4; ++g) av[g] = us2f(gs[g]);
                acc[mt][nt] = av;
            }

        // ---- MFMA: 16 kt x (2 LDS B-frags + 4 mfma), weights in regs ----
#pragma unroll
        for (int kt = 0; kt < 16; ++kt) {
            bf8v bfv[2];
#pragma unroll
            for (int nt = 0; nt < 2; ++nt) {
                int bl = nt * 16 + lo16;
                int c  = kt * 4 + hi4;
                bfv[nt] = *reinterpret_cast<const bf8v*>(
                    &hl[bl * 512 + ((c ^ (bl & 7)) << 3)]);
            }
#pragma unroll
            for (int mt = 0; mt < 2; ++mt)
#pragma unroll
                for (int nt = 0; nt < 2; ++nt)
                    acc[mt][nt] = __builtin_amdgcn_mfma_f32_16x16x32_bf16(
                        afr[mt][kt], bfv[nt], acc[mt][nt], 0, 0, 0);
        }

        // ---- pointwise: lane owns (u,b), 4 gates in regs; write h to bounce ----
#pragma unroll
        for (int mt = 0; mt < 2; ++mt)
#pragma unroll
            for (int nt = 0; nt < 2; ++nt) {
                bool msk = (t < len_[nt]);
                float i_ = sigm(acc[mt][nt][0]);
                float j_ = tanhf(acc[mt][nt][1]);
                float f_ = sigm(acc[mt][nt][2] + 1.0f);   // FORGET_BIAS
                float o_ = sigm(acc[mt][nt][3]);
                float cn = f_ * c_st[mt][nt] + i_ * j_;
                float hn = o_ * tanhf(cn);
                if (msk) c_st[mt][nt] = cn;
                h_st[mt][nt] = msk ? hn : h_st[mt][nt];
                hout[(nt * 16 + lo16) * 64 + w * 8 + mt * 4 + hi4] = f2us(h_st[mt][nt]);
            }
        __syncthreads();

        // ---- coalesced h_{t+1} stores: 512 x 8B ----
        {
            int bl = tid >> 4, uq = (tid & 15) * 4;
            ull v = *reinterpret_cast<const ull*>(&hout[bl * 64 + uq]);
            unsigned short* hdst = hbuf + ((size_t)(((t + 1) & 1) * 2 + d) * 64
                                           + bh * 32 + bl) * 512 + cg * 64 + uq;
            __hip_atomic_store(reinterpret_cast<ull*>(hdst), v,
                               __ATOMIC_RELAXED, __HIP_MEMORY_SCOPE_AGENT);
        }
        asm volatile("s_waitcnt vmcnt(0)" ::: "memory");
        __syncthreads();
        if (tid == 0)
            __hip_atomic_store(&flags[(size_t)t * 32 + (d * 2 + bh) * 8 + cg], 1u,
                               __ATOMIC_RELAXED, __HIP_MEMORY_SCOPE_AGENT);

        // ---- shadow: hcat stores ----
#pragma unroll
        for (int mt = 0; mt < 2; ++mt)
#pragma unroll
            for (int nt = 0; nt < 2; ++nt) {
                int b = bh * 32 + nt * 16 + lo16;
                int u = u0 + mt * 4 + hi4;
                bool msk = (t < len_[nt]);
                int p = (d == 1 && msk) ? (len_[nt] - 1 - t) : t;
                hcat[((size_t)p * 64 + b) * TWOH + (size_t)d * 512 + u] =
                    __float2bfloat16(msk ? h_st[mt][nt] : 0.f);
            }
    }
}

// ---------------- dense + softmax: out[b][s][c] ----------------
__global__ __launch_bounds__(256)
void dense_softmax(const bf16* __restrict__ h, const float* __restrict__ wd,
                   const float* __restrict__ bd, float* __restrict__ out)
{
    __shared__ __align__(16) bf16 wdT[NCLS][1032];
    for (int i = threadIdx.x; i < TWOH * NCLS; i += 256) {
        int k = i / NCLS, c = i % NCLS;    // wd[k][c]
        wdT[c][k] = __float2bfloat16(wd[i]);
    }
    __syncthreads();
    const int c  = threadIdx.x & 31;
    const int rl = threadIdx.x >> 5;
#pragma unroll 1
    for (int pass = 0; pass < 8; ++pass) {
        int r = blockIdx.x * 64 + pass * 8 + rl;   // r = s*BATCH + b
        const bf16* hrow = h + (size_t)r * TWOH;
        float acc = -1e30f;
        if (c < NCLS) {
            acc = 0.f;
            for (int k = 0; k < TWOH; k += 8) {
                uint4 hv = *reinterpret_cast<const uint4*>(hrow + k);
                uint4 wv = *reinterpret_cast<const uint4*>(&wdT[c][k]);
                const unsigned short* hs  = reinterpret_cast<const unsigned short*>(&hv);
                const unsigned short* wsp = reinterpret_cast<const unsigned short*>(&wv);
#pragma unroll
                for (int j = 0; j < 8; ++j) acc += us2f(hs[j]) * us2f(wsp[j]);
            }
            acc += bd[c];
        }
        float mx = acc;
#pragma unroll
        for (int o = 16; o; o >>= 1) mx = fmaxf(mx, __shfl_xor(mx, o, 32));
        float e = (c < NCLS) ? __expf(acc - mx) : 0.f;
        float sm = e;
#pragma unroll
        for (int o = 16; o; o >>= 1) sm += __shfl_xor(sm, o, 32);
        if (c < NCLS) {
            int s = r >> 6, b = r & 63;
            out[((size_t)b * S_LEN + s) * NCLS + c] = e / sm;
        }
    }
}

extern "C" void kernel_launch(void* const* d_in, const int* in_sizes, int n_in,
                              void* d_out, int out_size, void* d_ws, size_t ws_size,
                              hipStream_t stream)
{
    const int*   ids   = (const int*)  d_in[0];
    const int*   lens  = (const int*)  d_in[1];
    const float* emb   = (const float*)d_in[2];
    const float* w_fw0 = (const float*)d_in[3];
    const float* b_fw0 = (const float*)d_in[4];
    const float* w_bw0 = (const float*)d_in[5];
    const float* b_bw0 = (const float*)d_in[6];
    const float* w_fw1 = (const float*)d_in[7];
    const float* b_fw1 = (const float*)d_in[8];
    const float* w_bw1 = (const float*)d_in[9];
    const float* b_bw1 = (const float*)d_in[10];
    const float* wd    = (const float*)d_in[11];
    const float* bd    = (const float*)d_in[12];
    float* out = (float*)d_out;

    char* ws = (char*)d_ws;
    size_t off = 0;
    auto alloc = [&](size_t bytes) {
        void* p = ws + off;
        off += (bytes + 255) & ~(size_t)255;
        return p;
    };
    bf16*  x      = (bf16*) alloc((size_t)S_LEN * BATCH * EPAD * 2);
    bf16*  G4     = (bf16*) alloc((size_t)2 * S_LEN * BATCH * G4H * 2);
    bf16*  hcat0  = (bf16*) alloc((size_t)S_LEN * BATCH * TWOH * 2);
    bf16*  hcat1  = (bf16*) alloc((size_t)S_LEN * BATCH * TWOH * 2);
    bf16*  whTb   = (bf16*) alloc((size_t)4 * 512 * 4 * 512 * 2);
    bf16*  wxTb   = (bf16*) alloc((size_t)4 * G4H * 1024 * 2);
    unsigned short* hbuf = (unsigned short*)alloc((size_t)2 * 2 * BATCH * HID * 2);
    unsigned int* flags  = (unsigned int*) alloc((size_t)S_LEN * 32 * 4);

    embed_kernel<<<S_LEN * BATCH, 128, 0, stream>>>(ids, emb, x);
    wtrans_kernel<<<dim3(16, 64, 4), dim3(32, 32), 0, stream>>>(w_fw0, w_bw0, w_fw1, w_bw1, whTb);
    wxtrans_kernel<<<dim3(32, 64, 4), dim3(32, 32), 0, stream>>>(w_fw0, w_bw0, w_fw1, w_bw1, wxTb);

    for (int layer = 0; layer < 2; ++layer) {
        hipMemsetAsync(hbuf, 0, (size_t)2 * 2 * BATCH * HID * 2, stream);
        hipMemsetAsync(flags, 0, (size_t)S_LEN * 32 * 4, stream);
        const bf16* Ain   = layer ? hcat0 : x;
        int strideA       = layer ? TWOH : EPAD;
        int K             = layer ? 1024 : EPAD;
        const float* bfp  = layer ? b_fw1 : b_fw0;
        const float* bbp  = layer ? b_bw1 : b_bw0;
        bf16* hcat        = layer ? hcat1 : hcat0;

        gates_mfma<<<dim3(128, 16, 2), 256, 0, stream>>>(
            Ain, strideA, K, wxTb + (size_t)layer * 2 * G4H * 1024,
            bfp, bbp, lens, G4);

        const bf16*  Gp   = G4;
        const bf16*  whp  = whTb + (size_t)layer * 2 * 512 * 4 * 512;
        const int*   lnp  = lens;
        unsigned short* hbp = hbuf;
        unsigned int* flp = flags;
        bf16*        hcp  = hcat;
        void* args[6] = { &Gp, &whp, &lnp, &hbp, &flp, &hcp };
        hipLaunchCooperativeKernel(lstm_seq, dim3(32), dim3(512), args, 0, stream);
    }
    dense_softmax<<<256, 256, 0, stream>>>(hcat1, wd, bd, out);

    (void)in_sizes; (void)n_in; (void)out_size; (void)ws_size;
}